// Round 9
// baseline (325.926 us; speedup 1.0000x reference)
//
#include <hip/hip_runtime.h>
#include <hip/hip_bf16.h>

#define HW 16384
#define CC 192
#define BB 8
#define NHD 4
#define HD 48

typedef __attribute__((ext_vector_type(8))) short  short8;
typedef __attribute__((ext_vector_type(4))) float  f32x4;

static __device__ __forceinline__ unsigned short f2bf(float f) {
  unsigned u = __float_as_uint(f);
  u += 0x7fffu + ((u >> 16) & 1u);          // round-to-nearest-even
  return (unsigned short)(u >> 16);
}
// two fp32 -> packed bf16x2 (compiler emits v_cvt_pk_bf16_f32)
static __device__ __forceinline__ unsigned pk2bf(float lo, float hi) {
  __hip_bfloat162 h = __float22bfloat162_rn(make_float2(lo, hi));
  return *reinterpret_cast<unsigned*>(&h);
}

// lgkm-only barrier: LDS visibility without draining vmcnt (T4).
static __device__ __forceinline__ void ldsbar() {
  asm volatile("" ::: "memory");
  asm volatile("s_waitcnt lgkmcnt(0)" ::: "memory");
  __builtin_amdgcn_s_barrier();
  asm volatile("" ::: "memory");
}

// Cast Wq (192x192) and Wk (= Wkv rows 0..191) fp32 -> bf16, contiguous.
__global__ __launch_bounds__(256) void cast_w_kernel(
    const float* __restrict__ Wq, const float* __restrict__ Wkv,
    unsigned short* __restrict__ Wb)
{
  const int i = blockIdx.x * 256 + threadIdx.x;   // 0 .. 2*CC*CC-1
  const float v = (i < CC*CC) ? Wq[i] : Wkv[i - CC*CC];
  Wb[i] = f2bf(v);
}

// ---------------------------------------------------------------------------
// Fused q-proj + k-proj + gram, v2: 32-position tiles, q and k staged into
// SEPARATE LDS buffers (no WAR between them -> 2 barriers per tile), one
// combined q+k prefetch batch in flight across the whole compute phase.
// LDS: Xsq+Xsk 25.6K + QN/KN 26.1K = 51.7K -> 3 blocks/CU (12 waves/CU).
// Per block: 128 positions = 4 tiles of 32. Gram partials: 128 slots.
// ---------------------------------------------------------------------------
__global__ __launch_bounds__(256, 3) void qkg_kernel(
    const float* __restrict__ x_q, const float* __restrict__ x_k,
    const unsigned short* __restrict__ wb,   // [2][CC][CC] bf16 (Wq | Wk)
    const float* __restrict__ bq, const float* __restrict__ bkv,
    float* __restrict__ gpart)
{
  const int tid  = threadIdx.x;
  const int lane = tid & 63;
  const int wv   = tid >> 6;          // wave = head
  const int b    = blockIdx.y;
  const int p0   = blockIdx.x * 128;
  const int l15  = lane & 15;
  const int lg   = lane >> 4;

  __shared__ unsigned short Xsq[32][200];     // 12.8 KB
  __shared__ unsigned short Xsk[32][200];     // 12.8 KB
  __shared__ unsigned short QN[NHD][48][34];  // 13.06 KB (stride 17 dw: bank-clean)
  __shared__ unsigned short KN[NHD][48][34];  // 13.06 KB

  const float* Xq = x_q + (size_t)b*CC*HW;
  const float* Xk = x_k + (size_t)b*CC*HW;

  f32x4 pre[12];                      // q: [0..5], k: [6..11]
  auto LOADT2 = [&](int pb) {
    #pragma unroll
    for (int i = 0; i < 3; ++i) {
      const int it = tid + i*256;     // 768 = 96 ch-pairs x 8 pos-quads
      const int qd = it & 7, cp = it >> 3;
      const float* bq_ = Xq + (size_t)(2*cp)*HW + pb + qd*4;
      const float* bk_ = Xk + (size_t)(2*cp)*HW + pb + qd*4;
      pre[2*i]     = *(const f32x4*)(bq_);
      pre[2*i + 1] = *(const f32x4*)(bq_ + HW);
      pre[6 + 2*i]     = *(const f32x4*)(bk_);
      pre[6 + 2*i + 1] = *(const f32x4*)(bk_ + HW);
    }
  };
  auto WRITET2 = [&]() {
    #pragma unroll
    for (int i = 0; i < 3; ++i) {
      const int it = tid + i*256;
      const int qd = it & 7, cp = it >> 3;
      #pragma unroll
      for (int j = 0; j < 4; ++j) {
        *(unsigned*)&Xsq[qd*4 + j][2*cp] = pk2bf(pre[2*i][j], pre[2*i+1][j]);
        *(unsigned*)&Xsk[qd*4 + j][2*cp] = pk2bf(pre[6+2*i][j], pre[6+2*i+1][j]);
      }
    }
  };

  // Projection (48 rows x 32 cols) + bias + per-head l2norm -> DST bf16.
  auto PROJ32 = [&](const unsigned short* W, const float* bias,
                    unsigned short (*SRC)[200], unsigned short (*DST)[34]) {
    f32x4 acc[3][2];
    #pragma unroll
    for (int mt = 0; mt < 3; ++mt)
      #pragma unroll
      for (int nt = 0; nt < 2; ++nt)
        acc[mt][nt] = (f32x4){0.f, 0.f, 0.f, 0.f};

    #pragma unroll
    for (int kk = 0; kk < 6; ++kk) {
      short8 afr[3], bfr[2];
      #pragma unroll
      for (int mt = 0; mt < 3; ++mt)
        afr[mt] = *(const short8*)(W + (size_t)(wv*48 + mt*16 + l15)*CC + kk*32 + lg*8);
      #pragma unroll
      for (int nt = 0; nt < 2; ++nt)
        bfr[nt] = *(const short8*)&SRC[nt*16 + l15][kk*32 + lg*8];
      #pragma unroll
      for (int mt = 0; mt < 3; ++mt)
        #pragma unroll
        for (int nt = 0; nt < 2; ++nt)
          acc[mt][nt] = __builtin_amdgcn_mfma_f32_16x16x32_bf16(
              afr[mt], bfr[nt], acc[mt][nt], 0, 0, 0);
    }

    #pragma unroll
    for (int nt = 0; nt < 2; ++nt) {
      float v[3][4];
      float ss = 0.f;
      #pragma unroll
      for (int mt = 0; mt < 3; ++mt)
        #pragma unroll
        for (int r = 0; r < 4; ++r) {
          const float x = acc[mt][nt][r] + bias[wv*48 + mt*16 + lg*4 + r];
          v[mt][r] = x;
          ss += x*x;
        }
      ss += __shfl_xor(ss, 16);
      ss += __shfl_xor(ss, 32);
      const float rn = 1.0f / fmaxf(sqrtf(ss), 1e-12f);
      #pragma unroll
      for (int mt = 0; mt < 3; ++mt)
        #pragma unroll
        for (int r = 0; r < 4; ++r)
          DST[mt*16 + lg*4 + r][nt*16 + l15] = f2bf(v[mt][r] * rn);
    }
  };

  f32x4 gacc[3][3];
  #pragma unroll
  for (int mt = 0; mt < 3; ++mt)
    #pragma unroll
    for (int nt = 0; nt < 3; ++nt)
      gacc[mt][nt] = (f32x4){0.f, 0.f, 0.f, 0.f};

  LOADT2(p0);
  for (int t = 0; t < 4; ++t) {
    WRITET2();                           // drain t loads; pack q->Xsq, k->Xsk
    ldsbar();                            // staging visible to all waves
    if (t < 3) LOADT2(p0 + (t+1)*32);    // next q+k batch in flight all phase
    PROJ32(wb, bq, Xsq, QN[wv]);                 // q proj + norm
    PROJ32(wb + (size_t)CC*CC, bkv, Xsk, KN[wv]); // k proj + norm
    // gram: wave-private (own head's QN/KN), K=32 contraction
    {
      short8 ga[3], gb[3];
      #pragma unroll
      for (int mt = 0; mt < 3; ++mt)
        ga[mt] = *(const short8*)&QN[wv][mt*16 + l15][lg*8];
      #pragma unroll
      for (int nt = 0; nt < 3; ++nt)
        gb[nt] = *(const short8*)&KN[wv][nt*16 + l15][lg*8];
      #pragma unroll
      for (int mt = 0; mt < 3; ++mt)
        #pragma unroll
        for (int nt = 0; nt < 3; ++nt)
          gacc[mt][nt] = __builtin_amdgcn_mfma_f32_16x16x32_bf16(
              ga[mt], gb[nt], gacc[mt][nt], 0, 0, 0);
    }
    ldsbar();                            // all waves done reading Xs -> reuse
  }

  // 48x48 gram partial for (b, head=wv), slot = blockIdx.x (0..127)
  float* G = gpart + ((size_t)(b*NHD + wv)*128 + blockIdx.x)*2304;
  #pragma unroll
  for (int mt = 0; mt < 3; ++mt)
    #pragma unroll
    for (int nt = 0; nt < 3; ++nt)
      #pragma unroll
      for (int r = 0; r < 4; ++r)
        G[(mt*16 + lg*4 + r)*HD + nt*16 + l15] = gacc[mt][nt][r];
}

// Final projection: out = W3_b @ x_k + b3_b (pipelined, dbuf, lgkm barriers).
__global__ __launch_bounds__(256) void proj_fin(
    const float* __restrict__ x_k,
    const unsigned short* __restrict__ w3b,
    const float* __restrict__ b3,
    float* __restrict__ of)
{
  const int tid  = threadIdx.x;
  const int lane = tid & 63;
  const int wv   = tid >> 6;
  const int b    = blockIdx.y;
  const int p0   = blockIdx.x * 256;
  const int l15  = lane & 15;
  const int lg   = lane >> 4;
  const int qd   = tid & 15;

  __shared__ unsigned short Xt[2][64][200];

  const float* X = x_k + (size_t)b*CC*HW;
  const unsigned short* Wb = w3b + (size_t)b*CC*CC;
  const float* bias = b3 + (size_t)b*CC;

  short8 afr[6][3];
  #pragma unroll
  for (int kk = 0; kk < 6; ++kk)
    #pragma unroll
    for (int mt = 0; mt < 3; ++mt)
      afr[kk][mt] = *(const short8*)(Wb + (size_t)(wv*48 + mt*16 + l15)*CC + kk*32 + lg*8);

  float bv[3][4];
  #pragma unroll
  for (int mt = 0; mt < 3; ++mt)
    #pragma unroll
    for (int r = 0; r < 4; ++r)
      bv[mt][r] = bias[wv*48 + mt*16 + lg*4 + r];

  f32x4 pre[12];
  auto LOADT = [&](int pb) {
    #pragma unroll
    for (int i = 0; i < 6; ++i) {
      const int cp = (tid >> 4) + i*16;
      const float* base = X + (size_t)(2*cp)*HW + pb + qd*4;
      pre[2*i]   = *(const f32x4*)(base);
      pre[2*i+1] = *(const f32x4*)(base + HW);
    }
  };
  auto WRITET = [&](int buf) {
    #pragma unroll
    for (int i = 0; i < 6; ++i) {
      const int cp = (tid >> 4) + i*16;
      #pragma unroll
      for (int j = 0; j < 4; ++j)
        *(unsigned*)&Xt[buf][qd*4 + j][2*cp] = pk2bf(pre[2*i][j], pre[2*i+1][j]);
    }
  };

  float* Ofp = of + (size_t)b*CC*HW;

  auto COMPUTE = [&](int buf, int pb) {
    f32x4 acc[3][4];
    #pragma unroll
    for (int mt = 0; mt < 3; ++mt)
      #pragma unroll
      for (int nt = 0; nt < 4; ++nt)
        acc[mt][nt] = (f32x4){0.f, 0.f, 0.f, 0.f};

    #pragma unroll
    for (int kk = 0; kk < 6; ++kk) {
      short8 bfr[4];
      #pragma unroll
      for (int nt = 0; nt < 4; ++nt)
        bfr[nt] = *(const short8*)&Xt[buf][nt*16 + l15][kk*32 + lg*8];
      #pragma unroll
      for (int mt = 0; mt < 3; ++mt)
        #pragma unroll
        for (int nt = 0; nt < 4; ++nt)
          acc[mt][nt] = __builtin_amdgcn_mfma_f32_16x16x32_bf16(
              afr[kk][mt], bfr[nt], acc[mt][nt], 0, 0, 0);
    }

    #pragma unroll
    for (int nt = 0; nt < 4; ++nt) {
      const int col = pb + nt*16 + l15;
      #pragma unroll
      for (int mt = 0; mt < 3; ++mt)
        #pragma unroll
        for (int r = 0; r < 4; ++r)
          Ofp[(size_t)(wv*48 + mt*16 + lg*4 + r)*HW + col] = acc[mt][nt][r] + bv[mt][r];
    }
  };

  LOADT(p0);
  WRITET(0);
  ldsbar();
  #pragma unroll
  for (int t = 0; t < 4; ++t) {
    if (t < 3) LOADT(p0 + (t+1)*64);
    COMPUTE(t & 1, p0 + t*64);
    if (t < 3) {
      WRITET((t & 1) ^ 1);
      ldsbar();
    }
  }
}

// Per (b,h): reduce 128 gram partials, wave-parallel row softmax, then
// M[b][o][h*48+k] = sum_c Wp[o][h*48+c] * attn[c][k]  (fp32 out).
__global__ __launch_bounds__(256) void attn_m_kernel(
    const float* __restrict__ Gpart,
    const float* __restrict__ Wp,
    const float* __restrict__ temp,
    float* __restrict__ Mf)
{
  __shared__ float att[HD][52];
  const int bh  = blockIdx.x;          // 0..31
  const int b   = bh >> 2, h = bh & 3;
  const int tid = threadIdx.x;
  const float* src = Gpart + (size_t)bh*128*2304;

  #pragma unroll
  for (int i = 0; i < 9; ++i) {
    const int e = tid + i*256;         // 2304 = 9*256
    float s = 0.f;
    for (int k = 0; k < 128; ++k) s += src[(size_t)k*2304 + e];
    att[e/48][e%48] = s;
  }
  __syncthreads();

  const int g = tid >> 2, sl = tid & 3;
  if (g < HD) {
    const float t = temp[h];
    const float scale = 0.1f / (1.0f + expf(-t));   // 0.1*sigmoid(t)
    float* row = att[g];
    float m = -1e30f;
    #pragma unroll
    for (int jj = 0; jj < 12; ++jj) m = fmaxf(m, row[sl + jj*4]);
    m = fmaxf(m, __shfl_xor(m, 1));
    m = fmaxf(m, __shfl_xor(m, 2));
    float ev[12];
    float s = 0.f;
    #pragma unroll
    for (int jj = 0; jj < 12; ++jj) {
      const float e = expf((row[sl + jj*4] - m) * scale);
      ev[jj] = e; s += e;
    }
    s += __shfl_xor(s, 1);
    s += __shfl_xor(s, 2);
    const float inv = 1.0f / s;
    #pragma unroll
    for (int jj = 0; jj < 12; ++jj) row[sl + jj*4] = ev[jj] * inv;
  }
  __syncthreads();

  #pragma unroll
  for (int i = 0; i < 36; ++i) {
    const int idx = tid + i*256;
    const int o = idx / HD, k2 = idx % HD;
    const float* wrow = Wp + (size_t)o*CC + h*HD;
    float s = 0.f;
    #pragma unroll
    for (int c = 0; c < HD; ++c) s += wrow[c] * att[c][k2];
    Mf[(size_t)b*CC*CC + (size_t)o*CC + h*HD + k2] = s;
  }
}

// W3_b = M_b @ Wv (bf16 out), b3_b = M_b @ bv + bp (fp32).
__global__ __launch_bounds__(192) void w3_kernel(
    const float* __restrict__ Mf, const float* __restrict__ Wkv,
    const float* __restrict__ bkv, const float* __restrict__ bp,
    unsigned short* __restrict__ W3b, float* __restrict__ b3)
{
  const int b  = blockIdx.x;
  const int o0 = blockIdx.y * 8;
  const int j  = threadIdx.x;
  const float* M  = Mf + ((size_t)b*CC + o0)*CC;
  const float* Wv = Wkv + (size_t)CC*CC;
  const float* bv = bkv + CC;

  float acc[8]  = {0.f,0.f,0.f,0.f,0.f,0.f,0.f,0.f};
  float bacc[8] = {0.f,0.f,0.f,0.f,0.f,0.f,0.f,0.f};
  #pragma unroll 4
  for (int k = 0; k < CC; ++k) {
    const float w  = Wv[(size_t)k*CC + j];
    const float bk = bv[k];
    #pragma unroll
    for (int r = 0; r < 8; ++r) {
      const float m = M[r*CC + k];
      acc[r]  += m * w;
      bacc[r] += m * bk;
    }
  }
  unsigned short* dst = W3b + ((size_t)b*CC + o0)*CC + j;
  #pragma unroll
  for (int r = 0; r < 8; ++r) dst[(size_t)r*CC] = f2bf(acc[r]);
  if (j < 8) b3[(size_t)b*CC + o0 + j] = bacc[j] + bp[o0 + j];
}

extern "C" void kernel_launch(void* const* d_in, const int* in_sizes, int n_in,
                              void* d_out, int out_size, void* d_ws, size_t ws_size,
                              hipStream_t stream)
{
  (void)in_sizes; (void)n_in; (void)out_size; (void)ws_size;
  const float* x_q  = (const float*)d_in[0];
  const float* x_k  = (const float*)d_in[1];
  const float* Wq   = (const float*)d_in[2];
  const float* bq   = (const float*)d_in[3];
  const float* Wkv  = (const float*)d_in[4];
  const float* bkv  = (const float*)d_in[5];
  const float* Wp   = (const float*)d_in[6];
  const float* bp   = (const float*)d_in[7];
  const float* temp = (const float*)d_in[8];

  char* p = (char*)d_ws;
  float* gpart = (float*)p;                 p += (size_t)BB*NHD*128*2304*sizeof(float);
  float* mf = (float*)p;                    p += (size_t)BB*CC*CC*sizeof(float);
  unsigned short* w3b = (unsigned short*)p; p += (size_t)BB*CC*CC*sizeof(unsigned short);
  float* b3 = (float*)p;                    p += (size_t)BB*CC*sizeof(float);
  unsigned short* wb = (unsigned short*)p;  // 2*CC*CC bf16 (Wq | Wk)

  cast_w_kernel<<<dim3((2*CC*CC)/256), 256, 0, stream>>>(Wq, Wkv, wb);

  // fused q-proj + k-proj + gram (qn/kn stay in LDS)
  qkg_kernel<<<dim3(HW/128, BB), 256, 0, stream>>>(
      x_q, x_k, wb, bq, bkv, gpart);

  attn_m_kernel<<<dim3(BB*NHD), 256, 0, stream>>>(gpart, Wp, temp, mf);
  w3_kernel<<<dim3(BB, 24), 192, 0, stream>>>(mf, Wkv, bkv, bp, w3b, b3);

  // final: out = W3_b @ x_k + b3_b
  proj_fin<<<dim3(HW/256, BB), 256, 0, stream>>>(x_k, w3b, b3, (float*)d_out);
}

// Round 10
// 168.089 us; speedup vs baseline: 1.9390x; 1.9390x over previous
//
#include <hip/hip_runtime.h>
#include <hip/hip_bf16.h>

#define HW 16384
#define CC 192
#define BB 8
#define NHD 4
#define HD 48

typedef __attribute__((ext_vector_type(8))) short  short8;
typedef __attribute__((ext_vector_type(4))) float  f32x4;

static __device__ __forceinline__ unsigned short f2bf(float f) {
  unsigned u = __float_as_uint(f);
  u += 0x7fffu + ((u >> 16) & 1u);          // round-to-nearest-even
  return (unsigned short)(u >> 16);
}
// two fp32 -> packed bf16x2 (compiler emits v_cvt_pk_bf16_f32)
static __device__ __forceinline__ unsigned pk2bf(float lo, float hi) {
  __hip_bfloat162 h = __float22bfloat162_rn(make_float2(lo, hi));
  return *reinterpret_cast<unsigned*>(&h);
}

// lgkm-only barrier: LDS visibility without draining vmcnt (T4).
static __device__ __forceinline__ void ldsbar() {
  asm volatile("" ::: "memory");
  asm volatile("s_waitcnt lgkmcnt(0)" ::: "memory");
  __builtin_amdgcn_s_barrier();
  asm volatile("" ::: "memory");
}

// XOR swizzle for the staging buffers (row stride 100 dwords):
// plain writes collapse to 8 banks (row term = 16*(qd&1) only). Injecting
// row bits (row>>3)&3 into column dword bits 2-3 spreads each store over
// 32 banks (2 lanes/bank = free). Involution; b128-aligned (bits 2-3 only).
#define SWZ_COL(row, cdw) ((cdw) ^ ((((row) >> 3) & 3) << 2))

// Cast Wq (192x192) and Wk (= Wkv rows 0..191) fp32 -> bf16, contiguous.
__global__ __launch_bounds__(256) void cast_w_kernel(
    const float* __restrict__ Wq, const float* __restrict__ Wkv,
    unsigned short* __restrict__ Wb)
{
  const int i = blockIdx.x * 256 + threadIdx.x;   // 0 .. 2*CC*CC-1
  const float v = (i < CC*CC) ? Wq[i] : Wkv[i - CC*CC];
  Wb[i] = f2bf(v);
}

// ---------------------------------------------------------------------------
// Fused q-proj + k-proj + gram (R8 structure + Xs XOR swizzle).
// Per block: 256 positions (4 tiles of 64), wave = head. qn/kn live only in
// LDS; gram partials accumulated in regs across tiles, written once.
// ---------------------------------------------------------------------------
__global__ __launch_bounds__(256, 2) void qkg_kernel(
    const float* __restrict__ x_q, const float* __restrict__ x_k,
    const unsigned short* __restrict__ wb,   // [2][CC][CC] bf16 (Wq | Wk)
    const float* __restrict__ bq, const float* __restrict__ bkv,
    float* __restrict__ gpart)
{
  const int tid  = threadIdx.x;
  const int lane = tid & 63;
  const int wv   = tid >> 6;          // wave = head
  const int b    = blockIdx.y;
  const int p0   = blockIdx.x * 256;
  const int l15  = lane & 15;
  const int lg   = lane >> 4;
  const int qd   = tid & 15;

  __shared__ unsigned short Xs[64][200];      // 25.6 KB, swizzled staging
  __shared__ unsigned short QN[NHD][48][68];  // 26.1 KB
  __shared__ unsigned short KN[NHD][48][68];  // 26.1 KB

  const float* Xq = x_q + (size_t)b*CC*HW;
  const float* Xk = x_k + (size_t)b*CC*HW;

  f32x4 pre[12];
  auto LOADT = [&](const float* X, int pb) {
    #pragma unroll
    for (int i = 0; i < 6; ++i) {
      const int cp = (tid >> 4) + i*16;
      const float* base = X + (size_t)(2*cp)*HW + pb + qd*4;
      pre[2*i]   = *(const f32x4*)(base);
      pre[2*i+1] = *(const f32x4*)(base + HW);
    }
  };
  auto WRITET = [&]() {
    #pragma unroll
    for (int i = 0; i < 6; ++i) {
      const int cp = (tid >> 4) + i*16;
      #pragma unroll
      for (int j = 0; j < 4; ++j) {
        const int row = qd*4 + j;
        *(unsigned*)&Xs[row][2*SWZ_COL(row, cp)] =
            pk2bf(pre[2*i][j], pre[2*i+1][j]);
      }
    }
  };

  // Projection + bias + l2norm; result -> DST[c_local][p_local] (bf16).
  auto PROJ = [&](const unsigned short* W, const float* bias,
                  unsigned short (*DST)[68]) {
    f32x4 acc[3][4];
    #pragma unroll
    for (int mt = 0; mt < 3; ++mt)
      #pragma unroll
      for (int nt = 0; nt < 4; ++nt)
        acc[mt][nt] = (f32x4){0.f, 0.f, 0.f, 0.f};

    #pragma unroll
    for (int kk = 0; kk < 6; ++kk) {
      short8 afr[3], bfr[4];
      #pragma unroll
      for (int mt = 0; mt < 3; ++mt)
        afr[mt] = *(const short8*)(W + (size_t)(wv*48 + mt*16 + l15)*CC + kk*32 + lg*8);
      #pragma unroll
      for (int nt = 0; nt < 4; ++nt) {
        const int lgs = lg ^ ((2*nt + (l15 >> 3)) & 3);   // read-side swizzle
        bfr[nt] = *(const short8*)&Xs[nt*16 + l15][kk*32 + lgs*8];
      }
      #pragma unroll
      for (int mt = 0; mt < 3; ++mt)
        #pragma unroll
        for (int nt = 0; nt < 4; ++nt)
          acc[mt][nt] = __builtin_amdgcn_mfma_f32_16x16x32_bf16(
              afr[mt], bfr[nt], acc[mt][nt], 0, 0, 0);
    }

    #pragma unroll
    for (int nt = 0; nt < 4; ++nt) {
      float v[3][4];
      float ss = 0.f;
      #pragma unroll
      for (int mt = 0; mt < 3; ++mt)
        #pragma unroll
        for (int r = 0; r < 4; ++r) {
          const float x = acc[mt][nt][r] + bias[wv*48 + mt*16 + lg*4 + r];
          v[mt][r] = x;
          ss += x*x;
        }
      ss += __shfl_xor(ss, 16);
      ss += __shfl_xor(ss, 32);
      const float rn = 1.0f / fmaxf(sqrtf(ss), 1e-12f);
      #pragma unroll
      for (int mt = 0; mt < 3; ++mt)
        #pragma unroll
        for (int r = 0; r < 4; ++r)
          DST[mt*16 + lg*4 + r][nt*16 + l15] = f2bf(v[mt][r] * rn);
    }
  };

  f32x4 gacc[3][3];
  #pragma unroll
  for (int mt = 0; mt < 3; ++mt)
    #pragma unroll
    for (int nt = 0; nt < 3; ++nt)
      gacc[mt][nt] = (f32x4){0.f, 0.f, 0.f, 0.f};

  LOADT(Xq, p0);
  for (int t = 0; t < 4; ++t) {
    const int pb = p0 + t*64;
    WRITET();                          // q tile -> Xs (swizzled)
    ldsbar();
    LOADT(Xk, pb);                     // k loads in flight during q compute
    PROJ(wb, bq, QN[wv]);              // q: MFMA + norm -> QN
    ldsbar();                          // all waves done reading Xs(q)
    WRITET();                          // k tile -> Xs
    ldsbar();
    if (t < 3) LOADT(Xq, pb + 64);     // next q in flight during k compute
    PROJ(wb + (size_t)CC*CC, bkv, KN[wv]);  // k: MFMA + norm -> KN
    ldsbar();                          // (uniform barrier count across waves)

    // gram: wave-private (own head's QN/KN only) -> no barrier needed
    #pragma unroll
    for (int s = 0; s < 2; ++s) {
      short8 ga[3], gb[3];
      #pragma unroll
      for (int mt = 0; mt < 3; ++mt)
        ga[mt] = *(const short8*)&QN[wv][mt*16 + l15][s*32 + lg*8];
      #pragma unroll
      for (int nt = 0; nt < 3; ++nt)
        gb[nt] = *(const short8*)&KN[wv][nt*16 + l15][s*32 + lg*8];
      #pragma unroll
      for (int mt = 0; mt < 3; ++mt)
        #pragma unroll
        for (int nt = 0; nt < 3; ++nt)
          gacc[mt][nt] = __builtin_amdgcn_mfma_f32_16x16x32_bf16(
              ga[mt], gb[nt], gacc[mt][nt], 0, 0, 0);
    }
  }

  // write 48x48 gram partial for (b, head=wv), slot = blockIdx.x (0..63)
  float* G = gpart + ((size_t)(b*NHD + wv)*64 + blockIdx.x)*2304;
  #pragma unroll
  for (int mt = 0; mt < 3; ++mt)
    #pragma unroll
    for (int nt = 0; nt < 3; ++nt)
      #pragma unroll
      for (int r = 0; r < 4; ++r)
        G[(mt*16 + lg*4 + r)*HD + nt*16 + l15] = gacc[mt][nt][r];
}

// Final projection: out = W3_b @ x_k + b3_b (pipelined, dbuf, lgkm barriers,
// swizzled staging).
__global__ __launch_bounds__(256) void proj_fin(
    const float* __restrict__ x_k,
    const unsigned short* __restrict__ w3b,
    const float* __restrict__ b3,
    float* __restrict__ of)
{
  const int tid  = threadIdx.x;
  const int lane = tid & 63;
  const int wv   = tid >> 6;
  const int b    = blockIdx.y;
  const int p0   = blockIdx.x * 256;
  const int l15  = lane & 15;
  const int lg   = lane >> 4;
  const int qd   = tid & 15;

  __shared__ unsigned short Xt[2][64][200];

  const float* X = x_k + (size_t)b*CC*HW;
  const unsigned short* Wb = w3b + (size_t)b*CC*CC;
  const float* bias = b3 + (size_t)b*CC;

  short8 afr[6][3];
  #pragma unroll
  for (int kk = 0; kk < 6; ++kk)
    #pragma unroll
    for (int mt = 0; mt < 3; ++mt)
      afr[kk][mt] = *(const short8*)(Wb + (size_t)(wv*48 + mt*16 + l15)*CC + kk*32 + lg*8);

  float bv[3][4];
  #pragma unroll
  for (int mt = 0; mt < 3; ++mt)
    #pragma unroll
    for (int r = 0; r < 4; ++r)
      bv[mt][r] = bias[wv*48 + mt*16 + lg*4 + r];

  f32x4 pre[12];
  auto LOADT = [&](int pb) {
    #pragma unroll
    for (int i = 0; i < 6; ++i) {
      const int cp = (tid >> 4) + i*16;
      const float* base = X + (size_t)(2*cp)*HW + pb + qd*4;
      pre[2*i]   = *(const f32x4*)(base);
      pre[2*i+1] = *(const f32x4*)(base + HW);
    }
  };
  auto WRITET = [&](int buf) {
    #pragma unroll
    for (int i = 0; i < 6; ++i) {
      const int cp = (tid >> 4) + i*16;
      #pragma unroll
      for (int j = 0; j < 4; ++j) {
        const int row = qd*4 + j;
        *(unsigned*)&Xt[buf][row][2*SWZ_COL(row, cp)] =
            pk2bf(pre[2*i][j], pre[2*i+1][j]);
      }
    }
  };

  float* Ofp = of + (size_t)b*CC*HW;

  auto COMPUTE = [&](int buf, int pb) {
    f32x4 acc[3][4];
    #pragma unroll
    for (int mt = 0; mt < 3; ++mt)
      #pragma unroll
      for (int nt = 0; nt < 4; ++nt)
        acc[mt][nt] = (f32x4){0.f, 0.f, 0.f, 0.f};

    #pragma unroll
    for (int kk = 0; kk < 6; ++kk) {
      short8 bfr[4];
      #pragma unroll
      for (int nt = 0; nt < 4; ++nt) {
        const int lgs = lg ^ ((2*nt + (l15 >> 3)) & 3);   // read-side swizzle
        bfr[nt] = *(const short8*)&Xt[buf][nt*16 + l15][kk*32 + lgs*8];
      }
      #pragma unroll
      for (int mt = 0; mt < 3; ++mt)
        #pragma unroll
        for (int nt = 0; nt < 4; ++nt)
          acc[mt][nt] = __builtin_amdgcn_mfma_f32_16x16x32_bf16(
              afr[kk][mt], bfr[nt], acc[mt][nt], 0, 0, 0);
    }

    #pragma unroll
    for (int nt = 0; nt < 4; ++nt) {
      const int col = pb + nt*16 + l15;
      #pragma unroll
      for (int mt = 0; mt < 3; ++mt)
        #pragma unroll
        for (int r = 0; r < 4; ++r)
          Ofp[(size_t)(wv*48 + mt*16 + lg*4 + r)*HW + col] = acc[mt][nt][r] + bv[mt][r];
    }
  };

  LOADT(p0);
  WRITET(0);
  ldsbar();
  #pragma unroll
  for (int t = 0; t < 4; ++t) {
    if (t < 3) LOADT(p0 + (t+1)*64);
    COMPUTE(t & 1, p0 + t*64);
    if (t < 3) {
      WRITET((t & 1) ^ 1);
      ldsbar();
    }
  }
}

// Per (b,h): reduce 64 gram partials, wave-parallel row softmax, then
// M[b][o][h*48+k] = sum_c Wp[o][h*48+c] * attn[c][k]  (fp32 out).
__global__ __launch_bounds__(256) void attn_m_kernel(
    const float* __restrict__ Gpart,
    const float* __restrict__ Wp,
    const float* __restrict__ temp,
    float* __restrict__ Mf)
{
  __shared__ float att[HD][52];
  const int bh  = blockIdx.x;          // 0..31
  const int b   = bh >> 2, h = bh & 3;
  const int tid = threadIdx.x;
  const float* src = Gpart + (size_t)bh*64*2304;

  #pragma unroll
  for (int i = 0; i < 9; ++i) {
    const int e = tid + i*256;         // 2304 = 9*256
    float s = 0.f;
    #pragma unroll
    for (int k = 0; k < 64; ++k) s += src[(size_t)k*2304 + e];
    att[e/48][e%48] = s;
  }
  __syncthreads();

  const int g = tid >> 2, sl = tid & 3;
  if (g < HD) {
    const float t = temp[h];
    const float scale = 0.1f / (1.0f + expf(-t));   // 0.1*sigmoid(t)
    float* row = att[g];
    float m = -1e30f;
    #pragma unroll
    for (int jj = 0; jj < 12; ++jj) m = fmaxf(m, row[sl + jj*4]);
    m = fmaxf(m, __shfl_xor(m, 1));
    m = fmaxf(m, __shfl_xor(m, 2));
    float ev[12];
    float s = 0.f;
    #pragma unroll
    for (int jj = 0; jj < 12; ++jj) {
      const float e = expf((row[sl + jj*4] - m) * scale);
      ev[jj] = e; s += e;
    }
    s += __shfl_xor(s, 1);
    s += __shfl_xor(s, 2);
    const float inv = 1.0f / s;
    #pragma unroll
    for (int jj = 0; jj < 12; ++jj) row[sl + jj*4] = ev[jj] * inv;
  }
  __syncthreads();

  #pragma unroll
  for (int i = 0; i < 36; ++i) {
    const int idx = tid + i*256;
    const int o = idx / HD, k2 = idx % HD;
    const float* wrow = Wp + (size_t)o*CC + h*HD;
    float s = 0.f;
    #pragma unroll
    for (int c = 0; c < HD; ++c) s += wrow[c] * att[c][k2];
    Mf[(size_t)b*CC*CC + (size_t)o*CC + h*HD + k2] = s;
  }
}

// W3_b = M_b @ Wv (bf16 out), b3_b = M_b @ bv + bp (fp32).
__global__ __launch_bounds__(192) void w3_kernel(
    const float* __restrict__ Mf, const float* __restrict__ Wkv,
    const float* __restrict__ bkv, const float* __restrict__ bp,
    unsigned short* __restrict__ W3b, float* __restrict__ b3)
{
  const int b  = blockIdx.x;
  const int o0 = blockIdx.y * 8;
  const int j  = threadIdx.x;
  const float* M  = Mf + ((size_t)b*CC + o0)*CC;
  const float* Wv = Wkv + (size_t)CC*CC;
  const float* bv = bkv + CC;

  float acc[8]  = {0.f,0.f,0.f,0.f,0.f,0.f,0.f,0.f};
  float bacc[8] = {0.f,0.f,0.f,0.f,0.f,0.f,0.f,0.f};
  #pragma unroll 4
  for (int k = 0; k < CC; ++k) {
    const float w  = Wv[(size_t)k*CC + j];
    const float bk = bv[k];
    #pragma unroll
    for (int r = 0; r < 8; ++r) {
      const float m = M[r*CC + k];
      acc[r]  += m * w;
      bacc[r] += m * bk;
    }
  }
  unsigned short* dst = W3b + ((size_t)b*CC + o0)*CC + j;
  #pragma unroll
  for (int r = 0; r < 8; ++r) dst[(size_t)r*CC] = f2bf(acc[r]);
  if (j < 8) b3[(size_t)b*CC + o0 + j] = bacc[j] + bp[o0 + j];
}

extern "C" void kernel_launch(void* const* d_in, const int* in_sizes, int n_in,
                              void* d_out, int out_size, void* d_ws, size_t ws_size,
                              hipStream_t stream)
{
  (void)in_sizes; (void)n_in; (void)out_size; (void)ws_size;
  const float* x_q  = (const float*)d_in[0];
  const float* x_k  = (const float*)d_in[1];
  const float* Wq   = (const float*)d_in[2];
  const float* bq   = (const float*)d_in[3];
  const float* Wkv  = (const float*)d_in[4];
  const float* bkv  = (const float*)d_in[5];
  const float* Wp   = (const float*)d_in[6];
  const float* bp   = (const float*)d_in[7];
  const float* temp = (const float*)d_in[8];

  char* p = (char*)d_ws;
  float* gpart = (float*)p;                 p += (size_t)BB*NHD*64*2304*sizeof(float);
  float* mf = (float*)p;                    p += (size_t)BB*CC*CC*sizeof(float);
  unsigned short* w3b = (unsigned short*)p; p += (size_t)BB*CC*CC*sizeof(unsigned short);
  float* b3 = (float*)p;                    p += (size_t)BB*CC*sizeof(float);
  unsigned short* wb = (unsigned short*)p;  // 2*CC*CC bf16 (Wq | Wk)

  cast_w_kernel<<<dim3((2*CC*CC)/256), 256, 0, stream>>>(Wq, Wkv, wb);

  // fused q-proj + k-proj + gram (qn/kn stay in LDS)
  qkg_kernel<<<dim3(HW/256, BB), 256, 0, stream>>>(
      x_q, x_k, wb, bq, bkv, gpart);

  attn_m_kernel<<<dim3(BB*NHD), 256, 0, stream>>>(gpart, Wp, temp, mf);
  w3_kernel<<<dim3(BB, 24), 192, 0, stream>>>(mf, Wkv, bkv, bp, w3b, b3);

  // final: out = W3_b @ x_k + b3_b
  proj_fin<<<dim3(HW/256, BB), 256, 0, stream>>>(x_k, w3b, b3, (float*)d_out);
}